// Round 6
// baseline (302.733 us; speedup 1.0000x reference)
//
#include <hip/hip_runtime.h>
#include <math.h>

#define N_NODES 50000
#define N_EDGES 800000
#define D_IN    256
#define D_HID   128
#define D_OUT   64

// bucketed CSR build: bucket = dst >> 8 (256 nodes/bucket)
#define NB 196
#define CH 2048     // edges per scatter1 block
#define SLAB 4608   // per-bucket slab capacity (mean 4096 + 8 sigma)
#define NBLK1 12500 // node-blocks per chunk (4 nodes/block)

typedef unsigned int u32;
typedef unsigned short u16;
typedef __attribute__((ext_vector_type(8))) short bf16x8;   // 8 bf16 = 4 VGPRs
typedef __attribute__((ext_vector_type(4))) float f32x4;

__device__ __forceinline__ float bflo(u32 u) {
    union { u32 i; float f; } c; c.i = u << 16; return c.f;
}
__device__ __forceinline__ float bfhi(u32 u) {
    union { u32 i; float f; } c; c.i = u & 0xffff0000u; return c.f;
}
__device__ __forceinline__ u32 pack_bf2(float a, float b) {
    union { float f; u32 i; } ca, cb; ca.f = a; cb.f = b;
    u32 ra = (ca.i + 0x7fffu + ((ca.i >> 16) & 1u)) >> 16;
    u32 rb = (cb.i + 0x7fffu + ((cb.i >> 16) & 1u)) & 0xffff0000u;
    return ra | rb;
}

__device__ __forceinline__ void acc8(float* a, uint4 u) {
    a[0] += bflo(u.x); a[1] += bfhi(u.x);
    a[2] += bflo(u.y); a[3] += bfhi(u.y);
    a[4] += bflo(u.z); a[5] += bfhi(u.z);
    a[6] += bflo(u.w); a[7] += bfhi(u.w);
}

__device__ __forceinline__ int edge_at(const void* ei, int is64, int which, int i) {
    if (is64) return (int)((const long long*)ei)[(size_t)which * N_EDGES + i];
    return ((const int*)ei)[which * N_EDGES + i];
}

// per-block edge dtype detection: odd 32-bit words of the first 256 entries are
// all zero iff layout is int64 (values < 2^31).
__device__ __forceinline__ int detect_is64(const void* ei, int t, int* s_is32) {
    if (t == 0) *s_is32 = 0;
    __syncthreads();
    if (t < 256) {
        int vv = ((const int*)ei)[2 * t + 1];
        if (vv != 0) atomicOr(s_is32, 1);
    }
    __syncthreads();
    return (*s_is32 == 0);
}

// ---------------- bucketed CSR build (2 passes, slab-allocated) ----------------

// partition edges into per-bucket slabs of ebuf as packed (dst<<16)|src.
// bcur pre-initialized to slab bases (b*SLAB) by k_wsplit -> no histogram pass.
__global__ __launch_bounds__(256) void k_scatter1(const void* __restrict__ ei,
                                                  int* __restrict__ bcur,
                                                  u32* __restrict__ ebuf) {
    __shared__ int h[NB], gbase[NB], lc[NB];
    __shared__ int s_is32;
    int t = threadIdx.x;
    int is64 = detect_is64(ei, t, &s_is32);
    for (int i = t; i < NB; i += 256) { h[i] = 0; lc[i] = 0; }
    __syncthreads();
    int base = blockIdx.x * CH;

    u32 p[CH / 256];
    #pragma unroll
    for (int j = 0; j < CH / 256; ++j) {
        int i = base + j * 256 + t;
        if (i < N_EDGES) {
            int s = edge_at(ei, is64, 0, i);
            int d = edge_at(ei, is64, 1, i);
            p[j] = (u32)s | ((u32)d << 16);
            atomicAdd(&h[d >> 8], 1);
        }
    }
    __syncthreads();
    for (int i = t; i < NB; i += 256) if (h[i]) gbase[i] = atomicAdd(&bcur[i], h[i]);
    __syncthreads();
    #pragma unroll
    for (int j = 0; j < CH / 256; ++j) {
        int i = base + j * 256 + t;
        if (i < N_EDGES) {
            int b = (int)(p[j] >> 24);               // dst >> 8
            int lp = atomicAdd(&lc[b], 1);
            ebuf[gbase[b] + lp] = p[j];              // block-private contiguous run: L2-local
        }
    }
}

// per-bucket: LDS per-node counts/cursors; emit cnt, rowstart, dinv, colidx.
// colidx shares the slab geometry (gaps are fine: aggs use rowstart+cnt only).
__global__ __launch_bounds__(256) void k_scatter2(const u32* __restrict__ ebuf,
                                                  const int* __restrict__ bcur,
                                                  int* __restrict__ rowstart,
                                                  int* __restrict__ cnt,
                                                  float* __restrict__ dinv,
                                                  int* __restrict__ colidx) {
    __shared__ int h2[256], lofs[256], cur[256], sm[256];
    int b = blockIdx.x, t = threadIdx.x;
    int e0 = b * SLAB, ne = bcur[b] - e0;
    h2[t] = 0; cur[t] = 0;
    __syncthreads();
    for (int i = t; i < ne; i += 256) {
        u32 p = ebuf[e0 + i];
        atomicAdd(&h2[(p >> 16) & 255], 1);
    }
    __syncthreads();
    int v = h2[t]; sm[t] = v; __syncthreads();
    for (int off = 1; off < 256; off <<= 1) {
        int a = (t >= off) ? sm[t - off] : 0;
        __syncthreads();
        sm[t] += a;
        __syncthreads();
    }
    lofs[t] = sm[t] - v;
    __syncthreads();
    int node = (b << 8) + t;
    if (node < N_NODES) {
        rowstart[node] = e0 + lofs[t];
        cnt[node] = v;
        dinv[node] = rsqrtf(1.0f + (float)v);
    }
    for (int i = t; i < ne; i += 256) {
        u32 p = ebuf[e0 + i];
        int dl = (p >> 16) & 255;
        int lp = atomicAdd(&cur[dl], 1);
        colidx[e0 + lofs[dl] + lp] = (int)(p & 0xffffu);
    }
}

// ------ W pre-split (both layers, truncation split: hi+lo == w exactly in f32) ------
// also initializes bcur to slab bases (replaces histogram + memset dispatches).
__global__ void k_wsplit(const float* __restrict__ W1, u16* __restrict__ t1h,
                         u16* __restrict__ t1l, const float* __restrict__ W2,
                         u16* __restrict__ t2h, u16* __restrict__ t2l,
                         int* __restrict__ bcur) {
    int i = blockIdx.x * 256 + threadIdx.x;
    if (i < NB) bcur[i] = i * SLAB;
    if (i < D_IN * D_HID) {
        int k = i / D_HID, c = i - k * D_HID;
        u32 bits = __float_as_uint(W1[i]);
        u32 hb = bits & 0xffff0000u;
        float lo = __uint_as_float(bits) - __uint_as_float(hb);
        t1h[(size_t)c * D_IN + k] = (u16)(hb >> 16);
        t1l[(size_t)c * D_IN + k] = (u16)(__float_as_uint(lo) >> 16);
    }
    int j = i - D_IN * D_HID;
    if (j >= 0 && j < D_HID * D_OUT) {
        int k = j / D_OUT, c = j - k * D_OUT;
        u32 bits = __float_as_uint(W2[j]);
        u32 hb = bits & 0xffff0000u;
        float lo = __uint_as_float(bits) - __uint_as_float(hb);
        t2h[(size_t)c * D_HID + k] = (u16)(hb >> 16);
        t2l[(size_t)c * D_HID + k] = (u16)(__float_as_uint(lo) >> 16);
    }
}

// ---- MFMA GEMM (A = f32): Cp[r,:] = pack_bf16( (A[r,:]@W) * dinv[r] ) ----
// BM=128, 4 waves x (2x16 rows, NF cols). K-step 32. Trunc hi/lo split, 3-term MFMA.
template <int K, int NF>
__global__ __launch_bounds__(256) void k_gemm_f32a(
    const float* __restrict__ A, const u16* __restrict__ tHi,
    const u16* __restrict__ tLo, const float* __restrict__ dinv,
    u32* __restrict__ Cp, int M) {
    constexpr int NT = NF / 16;
    constexpr int LDK = 40;
    __shared__ u16 aH[128][LDK], aL[128][LDK];
    __shared__ u16 wH[NF][LDK], wL[NF][LDK];

    const int t = threadIdx.x;
    const int lane = t & 63, wv = t >> 6;
    const int m0 = blockIdx.x * 128;
    const int lr = lane & 15, lk = (lane >> 4) * 8;

    f32x4 acc[2][NT] = {};

    const int arow = t >> 1;
    const int akq = (t & 1) * 16;
    const bool aok = (m0 + arow) < M;
    const float* asrc = A + (size_t)(m0 + arow) * K + akq;

    for (int ks = 0; ks < K; ks += 32) {
        {
            float f[16];
            #pragma unroll
            for (int j = 0; j < 16; ++j) f[j] = 0.0f;
            if (aok) {
                const float4* p = (const float4*)(asrc + ks);
                float4 v0 = p[0], v1 = p[1], v2 = p[2], v3 = p[3];
                f[0] = v0.x; f[1] = v0.y; f[2]  = v0.z; f[3]  = v0.w;
                f[4] = v1.x; f[5] = v1.y; f[6]  = v1.z; f[7]  = v1.w;
                f[8] = v2.x; f[9] = v2.y; f[10] = v2.z; f[11] = v2.w;
                f[12] = v3.x; f[13] = v3.y; f[14] = v3.z; f[15] = v3.w;
            }
            u32 hp[8], lp[8];
            #pragma unroll
            for (int q = 0; q < 8; ++q) {
                u32 b0 = __float_as_uint(f[2 * q]);
                u32 b1 = __float_as_uint(f[2 * q + 1]);
                u32 h0 = b0 & 0xffff0000u, h1 = b1 & 0xffff0000u;
                float l0 = f[2 * q] - __uint_as_float(h0);
                float l1 = f[2 * q + 1] - __uint_as_float(h1);
                hp[q] = (h0 >> 16) | h1;
                lp[q] = (__float_as_uint(l0) >> 16) | (__float_as_uint(l1) & 0xffff0000u);
            }
            *(uint4*)&aH[arow][akq + 0] = make_uint4(hp[0], hp[1], hp[2], hp[3]);
            *(uint4*)&aH[arow][akq + 8] = make_uint4(hp[4], hp[5], hp[6], hp[7]);
            *(uint4*)&aL[arow][akq + 0] = make_uint4(lp[0], lp[1], lp[2], lp[3]);
            *(uint4*)&aL[arow][akq + 8] = make_uint4(lp[4], lp[5], lp[6], lp[7]);
        }
        #pragma unroll
        for (int idx = t; idx < NF * 4; idx += 256) {
            int col = idx >> 2;
            int k8 = (idx & 3) * 8;
            *(uint4*)&wH[col][k8] = *(const uint4*)&tHi[(size_t)col * K + ks + k8];
            *(uint4*)&wL[col][k8] = *(const uint4*)&tLo[(size_t)col * K + ks + k8];
        }
        __syncthreads();

        bf16x8 afH[2], afL[2];
        #pragma unroll
        for (int mt = 0; mt < 2; ++mt) {
            int r = wv * 32 + mt * 16 + lr;
            afH[mt] = *(const bf16x8*)&aH[r][lk];
            afL[mt] = *(const bf16x8*)&aL[r][lk];
        }
        #pragma unroll
        for (int nt = 0; nt < NT; ++nt) {
            bf16x8 bh = *(const bf16x8*)&wH[nt * 16 + lr][lk];
            bf16x8 bl = *(const bf16x8*)&wL[nt * 16 + lr][lk];
            #pragma unroll
            for (int mt = 0; mt < 2; ++mt) {
                acc[mt][nt] = __builtin_amdgcn_mfma_f32_16x16x32_bf16(afH[mt], bh, acc[mt][nt], 0, 0, 0);
                acc[mt][nt] = __builtin_amdgcn_mfma_f32_16x16x32_bf16(afL[mt], bh, acc[mt][nt], 0, 0, 0);
                acc[mt][nt] = __builtin_amdgcn_mfma_f32_16x16x32_bf16(afH[mt], bl, acc[mt][nt], 0, 0, 0);
            }
        }
        __syncthreads();
    }

    #pragma unroll
    for (int mt = 0; mt < 2; ++mt) {
        #pragma unroll
        for (int r = 0; r < 4; ++r) {
            int row = m0 + wv * 32 + mt * 16 + (lane >> 4) * 4 + r;
            float dv = (row < M) ? dinv[row] : 0.0f;
            #pragma unroll
            for (int nt = 0; nt < NT; ++nt) {
                float v = acc[mt][nt][r] * dv;
                float vn = __shfl_xor(v, 1);
                if (!(lane & 1) && row < M) {
                    Cp[(size_t)row * (NF / 2) + nt * 8 + (lr >> 1)] = pack_bf2(v, vn);
                }
            }
        }
    }
}

// ---- MFMA GEMM (A pre-split hi/lo, per-row gate g1 applied in staging) ----
template <int K, int NF>
__global__ __launch_bounds__(256) void k_gemm_splita(
    const u32* __restrict__ aHg, const u32* __restrict__ aLg,
    const float* __restrict__ g1,
    const u16* __restrict__ tHi, const u16* __restrict__ tLo,
    const float* __restrict__ dinv, u32* __restrict__ Cp, int M) {
    constexpr int NT = NF / 16;
    constexpr int LDK = 40;
    __shared__ u16 aH[128][LDK], aL[128][LDK];
    __shared__ u16 wH[NF][LDK], wL[NF][LDK];

    const int t = threadIdx.x;
    const int lane = t & 63, wv = t >> 6;
    const int m0 = blockIdx.x * 128;
    const int lr = lane & 15, lk = (lane >> 4) * 8;

    f32x4 acc[2][NT] = {};

    for (int ks = 0; ks < K; ks += 32) {
        #pragma unroll
        for (int idx = t; idx < 128 * 4; idx += 256) {
            int row = idx >> 2;
            int kq = (idx & 3) * 8;
            int grow = m0 + row;
            uint4 hv = make_uint4(0, 0, 0, 0), lv = make_uint4(0, 0, 0, 0);
            if (grow < M) {
                size_t gi = (size_t)grow * (K / 2) + (ks + kq) / 2;
                hv = *(const uint4*)&aHg[gi];
                lv = *(const uint4*)&aLg[gi];
                float gv = g1[grow];
                u32* hp = (u32*)&hv; u32* lp = (u32*)&lv;
                #pragma unroll
                for (int w2 = 0; w2 < 4; ++w2) {
                    float f0 = (bflo(hp[w2]) + bflo(lp[w2])) * gv;
                    float f1 = (bfhi(hp[w2]) + bfhi(lp[w2])) * gv;
                    u32 h0 = __float_as_uint(f0) & 0xffff0000u;
                    u32 h1b = __float_as_uint(f1) & 0xffff0000u;
                    float l0 = f0 - __uint_as_float(h0);
                    float l1 = f1 - __uint_as_float(h1b);
                    hp[w2] = (h0 >> 16) | h1b;
                    lp[w2] = (__float_as_uint(l0) >> 16) | (__float_as_uint(l1) & 0xffff0000u);
                }
            }
            *(uint4*)&aH[row][kq] = hv;
            *(uint4*)&aL[row][kq] = lv;
        }
        #pragma unroll
        for (int idx = t; idx < NF * 4; idx += 256) {
            int col = idx >> 2;
            int k8 = (idx & 3) * 8;
            *(uint4*)&wH[col][k8] = *(const uint4*)&tHi[(size_t)col * K + ks + k8];
            *(uint4*)&wL[col][k8] = *(const uint4*)&tLo[(size_t)col * K + ks + k8];
        }
        __syncthreads();

        bf16x8 afH[2], afL[2];
        #pragma unroll
        for (int mt = 0; mt < 2; ++mt) {
            int r = wv * 32 + mt * 16 + lr;
            afH[mt] = *(const bf16x8*)&aH[r][lk];
            afL[mt] = *(const bf16x8*)&aL[r][lk];
        }
        #pragma unroll
        for (int nt = 0; nt < NT; ++nt) {
            bf16x8 bh = *(const bf16x8*)&wH[nt * 16 + lr][lk];
            bf16x8 bl = *(const bf16x8*)&wL[nt * 16 + lr][lk];
            #pragma unroll
            for (int mt = 0; mt < 2; ++mt) {
                acc[mt][nt] = __builtin_amdgcn_mfma_f32_16x16x32_bf16(afH[mt], bh, acc[mt][nt], 0, 0, 0);
                acc[mt][nt] = __builtin_amdgcn_mfma_f32_16x16x32_bf16(afL[mt], bh, acc[mt][nt], 0, 0, 0);
                acc[mt][nt] = __builtin_amdgcn_mfma_f32_16x16x32_bf16(afH[mt], bl, acc[mt][nt], 0, 0, 0);
            }
        }
        __syncthreads();
    }

    #pragma unroll
    for (int mt = 0; mt < 2; ++mt) {
        #pragma unroll
        for (int r = 0; r < 4; ++r) {
            int row = m0 + wv * 32 + mt * 16 + (lane >> 4) * 4 + r;
            float dv = (row < M) ? dinv[row] : 0.0f;
            #pragma unroll
            for (int nt = 0; nt < NT; ++nt) {
                float v = acc[mt][nt][r] * dv;
                float vn = __shfl_xor(v, 1);
                if (!(lane & 1) && row < M) {
                    Cp[(size_t)row * (NF / 2) + nt * 8 + (lr >> 1)] = pack_bf2(v, vn);
                }
            }
        }
    }
}

// ---------------- feature-chunked aggregation ----------------
// Chunk = 64 B (one cache line) of a row. Chunk-pass line-set = 3.2 MB ->
// L2-resident per XCD. Chunk is the SLOW grid index so co-resident blocks
// share a chunk. Gate (sigmoid over full row) is decoupled via per-chunk
// partial dots (pdot) + tiny finalize kernels.

// layer 1: 128 feats -> 4 chunks x 32 feats. 16 neighbor-slots x 4 lanes/row.
// Emits PRE-GATE h1 (post relu, x dv, +bias) as trunc hi/lo, and pdot1 partials.
__global__ __launch_bounds__(256) void k_agg1c(
        const u32* __restrict__ hs, const int* __restrict__ rowstart,
        const int* __restrict__ cnt, const int* __restrict__ colidx,
        const float* __restrict__ dinv,
        const float* __restrict__ b, const float* __restrict__ aw,
        float* __restrict__ pdot,
        u32* __restrict__ oHi, u32* __restrict__ oLo) {
    int c  = blockIdx.x / NBLK1;
    int nb = blockIdx.x - c * NBLK1;
    int v = nb * 4 + (threadIdx.x >> 6);
    if (v >= N_NODES) return;
    int l = threadIdx.x & 63;
    int g = l >> 2, q = l & 3;              // 16 slots x 4 lanes (uint4 each)
    const uint4* hs4 = (const uint4*)hs;    // 16 uint4 per 128-feat row
    const int cb = c * 4 + q;
    float a[8];
    #pragma unroll
    for (int k = 0; k < 8; ++k) a[k] = 0.0f;
    if (g == 0) acc8(a, hs4[(size_t)v * 16 + cb]);   // self
    int start = rowstart[v], len = cnt[v];
    const int* cx = colidx + start;
    int jj = g;
    for (; jj + 16 < len; jj += 32) {
        int s0 = cx[jj], s1 = cx[jj + 16];
        uint4 u0 = hs4[(size_t)s0 * 16 + cb];
        uint4 u1 = hs4[(size_t)s1 * 16 + cb];
        acc8(a, u0); acc8(a, u1);
    }
    if (jj < len) acc8(a, hs4[(size_t)cx[jj] * 16 + cb]);
    #pragma unroll
    for (int k = 0; k < 8; ++k) {
        a[k] += __shfl_xor(a[k], 4);
        a[k] += __shfl_xor(a[k], 8);
        a[k] += __shfl_xor(a[k], 16);
        a[k] += __shfl_xor(a[k], 32);
    }
    float dv = dinv[v];
    const float* bc = b + c * 32 + q * 8;
    float4 b0 = *(const float4*)bc, b1 = *(const float4*)(bc + 4);
    a[0] = fmaxf(a[0] * dv + b0.x, 0.0f); a[1] = fmaxf(a[1] * dv + b0.y, 0.0f);
    a[2] = fmaxf(a[2] * dv + b0.z, 0.0f); a[3] = fmaxf(a[3] * dv + b0.w, 0.0f);
    a[4] = fmaxf(a[4] * dv + b1.x, 0.0f); a[5] = fmaxf(a[5] * dv + b1.y, 0.0f);
    a[6] = fmaxf(a[6] * dv + b1.z, 0.0f); a[7] = fmaxf(a[7] * dv + b1.w, 0.0f);
    const float* ac = aw + c * 32 + q * 8;
    float4 w0 = *(const float4*)ac, w1 = *(const float4*)(ac + 4);
    float p = a[0] * w0.x + a[1] * w0.y + a[2] * w0.z + a[3] * w0.w
            + a[4] * w1.x + a[5] * w1.y + a[6] * w1.z + a[7] * w1.w;
    p += __shfl_xor(p, 1); p += __shfl_xor(p, 2);
    if (l == 0) pdot[(size_t)c * N_NODES + v] = p;
    if (g == 0) {
        u32 hp[4], lp[4];
        #pragma unroll
        for (int pr = 0; pr < 4; ++pr) {
            float v0 = a[2 * pr], v1 = a[2 * pr + 1];
            u32 h0 = __float_as_uint(v0) & 0xffff0000u;
            u32 h1 = __float_as_uint(v1) & 0xffff0000u;
            float l0 = v0 - __uint_as_float(h0);
            float l1 = v1 - __uint_as_float(h1);
            hp[pr] = (h0 >> 16) | h1;
            lp[pr] = (__float_as_uint(l0) >> 16) | (__float_as_uint(l1) & 0xffff0000u);
        }
        *(uint4*)&oHi[(size_t)v * 64 + c * 16 + q * 4] = make_uint4(hp[0], hp[1], hp[2], hp[3]);
        *(uint4*)&oLo[(size_t)v * 64 + c * 16 + q * 4] = make_uint4(lp[0], lp[1], lp[2], lp[3]);
    }
}

// gate1: g1[v] = sigmoid(sum_c pdot1[c][v] + ab1)
__global__ void k_gate1(const float* __restrict__ pdot, const float* __restrict__ ab,
                        float* __restrict__ g1) {
    int v = blockIdx.x * 256 + threadIdx.x;
    if (v < N_NODES) {
        float p = pdot[v] + pdot[N_NODES + v] + pdot[2 * N_NODES + v]
                + pdot[3 * N_NODES + v] + ab[0];
        g1[v] = 1.0f / (1.0f + expf(-p));
    }
}

// layer 2: 64 feats -> 2 chunks x 32 feats. Emits pre-gate f32 h2a + pdot2.
__global__ __launch_bounds__(256) void k_agg2c(
        const u32* __restrict__ hs, const int* __restrict__ rowstart,
        const int* __restrict__ cnt, const int* __restrict__ colidx,
        const float* __restrict__ dinv,
        const float* __restrict__ b, const float* __restrict__ aw,
        float* __restrict__ pdot, float* __restrict__ h2a) {
    int c  = blockIdx.x / NBLK1;
    int nb = blockIdx.x - c * NBLK1;
    int v = nb * 4 + (threadIdx.x >> 6);
    if (v >= N_NODES) return;
    int l = threadIdx.x & 63;
    int g = l >> 2, q = l & 3;
    const uint4* hs4 = (const uint4*)hs;    // 8 uint4 per 64-feat row
    const int cb = c * 4 + q;
    float a[8];
    #pragma unroll
    for (int k = 0; k < 8; ++k) a[k] = 0.0f;
    if (g == 0) acc8(a, hs4[(size_t)v * 8 + cb]);   // self
    int start = rowstart[v], len = cnt[v];
    const int* cx = colidx + start;
    int jj = g;
    for (; jj + 16 < len; jj += 32) {
        int s0 = cx[jj], s1 = cx[jj + 16];
        uint4 u0 = hs4[(size_t)s0 * 8 + cb];
        uint4 u1 = hs4[(size_t)s1 * 8 + cb];
        acc8(a, u0); acc8(a, u1);
    }
    if (jj < len) acc8(a, hs4[(size_t)cx[jj] * 8 + cb]);
    #pragma unroll
    for (int k = 0; k < 8; ++k) {
        a[k] += __shfl_xor(a[k], 4);
        a[k] += __shfl_xor(a[k], 8);
        a[k] += __shfl_xor(a[k], 16);
        a[k] += __shfl_xor(a[k], 32);
    }
    float dv = dinv[v];
    const float* bc = b + c * 32 + q * 8;
    float4 b0 = *(const float4*)bc, b1 = *(const float4*)(bc + 4);
    a[0] = a[0] * dv + b0.x; a[1] = a[1] * dv + b0.y;
    a[2] = a[2] * dv + b0.z; a[3] = a[3] * dv + b0.w;
    a[4] = a[4] * dv + b1.x; a[5] = a[5] * dv + b1.y;
    a[6] = a[6] * dv + b1.z; a[7] = a[7] * dv + b1.w;
    const float* ac = aw + c * 32 + q * 8;
    float4 w0 = *(const float4*)ac, w1 = *(const float4*)(ac + 4);
    float p = a[0] * w0.x + a[1] * w0.y + a[2] * w0.z + a[3] * w0.w
            + a[4] * w1.x + a[5] * w1.y + a[6] * w1.z + a[7] * w1.w;
    p += __shfl_xor(p, 1); p += __shfl_xor(p, 2);
    if (l == 0) pdot[(size_t)c * N_NODES + v] = p;
    if (g == 0) {
        float* o = h2a + (size_t)v * 64 + c * 32 + q * 8;
        *(float4*)o       = make_float4(a[0], a[1], a[2], a[3]);
        *(float4*)(o + 4) = make_float4(a[4], a[5], a[6], a[7]);
    }
}

// gate2: out = h2a * sigmoid(sum_c pdot2[c][v] + ab2)
__global__ __launch_bounds__(256) void k_gate2(const float* __restrict__ h2a,
                                               const float* __restrict__ pdot,
                                               const float* __restrict__ ab,
                                               float* __restrict__ out) {
    int v = blockIdx.x * 4 + (threadIdx.x >> 6);
    int f = threadIdx.x & 63;
    if (v >= N_NODES) return;
    float p = pdot[v] + pdot[N_NODES + v] + ab[0];
    float g = 1.0f / (1.0f + expf(-p));
    out[(size_t)v * 64 + f] = h2a[(size_t)v * 64 + f] * g;
}

// ---------------- launch ----------------

static inline size_t align_up(size_t x, size_t a) { return (x + a - 1) & ~(a - 1); }

extern "C" void kernel_launch(void* const* d_in, const int* in_sizes, int n_in,
                              void* d_out, int out_size, void* d_ws, size_t ws_size,
                              hipStream_t stream) {
    const float* x   = (const float*)d_in[0];
    const void*  ei  = d_in[1];
    const float* W1  = (const float*)d_in[2];
    const float* b1  = (const float*)d_in[3];
    const float* W2  = (const float*)d_in[4];
    const float* b2  = (const float*)d_in[5];
    const float* aw1 = (const float*)d_in[6];
    const float* ab1 = (const float*)d_in[7];
    const float* aw2 = (const float*)d_in[8];
    const float* ab2 = (const float*)d_in[9];
    float* out = (float*)d_out;

    char* w = (char*)d_ws;
    size_t off = 0;
    int*   bcur     = (int*)(w + off); off = align_up(off + NB * 4, 256);
    int*   cnt      = (int*)(w + off); off = align_up(off + N_NODES * 4, 256);
    int*   rowstart = (int*)(w + off); off = align_up(off + N_NODES * 4, 256);
    float* dinv     = (float*)(w + off); off = align_up(off + N_NODES * 4, 256);
    u32*   ebuf     = (u32*)(w + off); off = align_up(off + (size_t)NB * SLAB * 4, 256);
    int*   colidx   = (int*)(w + off); off = align_up(off + (size_t)NB * SLAB * 4, 256);
    u32*   h1s      = (u32*)(w + off); off = align_up(off + (size_t)N_NODES * 64 * 4, 256);
    u32*   h1hi     = (u32*)(w + off); off = align_up(off + (size_t)N_NODES * 64 * 4, 256);
    u32*   h1lo     = (u32*)(w + off); off = align_up(off + (size_t)N_NODES * 64 * 4, 256);
    u32*   h2s      = (u32*)(w + off); off = align_up(off + (size_t)N_NODES * 32 * 4, 256);
    float* h2a      = (float*)(w + off); off = align_up(off + (size_t)N_NODES * 64 * 4, 256);
    float* pdot1    = (float*)(w + off); off = align_up(off + (size_t)4 * N_NODES * 4, 256);
    float* pdot2    = (float*)(w + off); off = align_up(off + (size_t)2 * N_NODES * 4, 256);
    float* g1       = (float*)(w + off); off = align_up(off + (size_t)N_NODES * 4, 256);
    u16*   wt1h     = (u16*)(w + off); off = align_up(off + (size_t)D_IN * D_HID * 2, 256);
    u16*   wt1l     = (u16*)(w + off); off = align_up(off + (size_t)D_IN * D_HID * 2, 256);
    u16*   wt2h     = (u16*)(w + off); off = align_up(off + (size_t)D_HID * D_OUT * 2, 256);
    u16*   wt2l     = (u16*)(w + off); off = align_up(off + (size_t)D_HID * D_OUT * 2, 256);
    (void)ws_size; (void)out_size; (void)n_in; (void)in_sizes;

    // wsplit also initializes bcur to slab bases (no memset / histogram dispatch)
    k_wsplit<<<(D_IN * D_HID + D_HID * D_OUT + 255) / 256, 256, 0, stream>>>(
        W1, wt1h, wt1l, W2, wt2h, wt2l, bcur);

    k_scatter1<<<(N_EDGES + CH - 1) / CH, 256, 0, stream>>>(ei, bcur, ebuf);
    k_scatter2<<<NB, 256, 0, stream>>>(ebuf, bcur, rowstart, cnt, dinv, colidx);

    // layer 1: h1s = pack_bf16((x @ W1) * dinv), split-bf16 MFMA
    k_gemm_f32a<D_IN, D_HID><<<(N_NODES + 127) / 128, 256, 0, stream>>>(
        x, wt1h, wt1l, dinv, h1s, N_NODES);
    k_agg1c<<<4 * NBLK1, 256, 0, stream>>>(
        h1s, rowstart, cnt, colidx, dinv, b1, aw1, pdot1, h1hi, h1lo);
    k_gate1<<<(N_NODES + 255) / 256, 256, 0, stream>>>(pdot1, ab1, g1);

    // layer 2: h2s = pack_bf16(((g1*h1) @ W2) * dinv), gate folded into staging
    k_gemm_splita<D_HID, D_OUT><<<(N_NODES + 127) / 128, 256, 0, stream>>>(
        h1hi, h1lo, g1, wt2h, wt2l, dinv, h2s, N_NODES);
    k_agg2c<<<2 * NBLK1, 256, 0, stream>>>(
        h2s, rowstart, cnt, colidx, dinv, b2, aw2, pdot2, h2a);
    k_gate2<<<(N_NODES + 3) / 4, 256, 0, stream>>>(h2a, pdot2, ab2, out);
}

// Round 7
// 225.783 us; speedup vs baseline: 1.3408x; 1.3408x over previous
//
#include <hip/hip_runtime.h>
#include <math.h>

#define N_NODES 50000
#define N_EDGES 800000
#define D_IN    256
#define D_HID   128
#define D_OUT   64

// bucketed CSR build: bucket = dst >> 8 (256 nodes/bucket)
#define NB 196
#define CH 2048     // edges per scatter1 block -> 391 blocks
#define SLAB 4608   // per-bucket slab capacity (mean 4096 + 8 sigma)

typedef unsigned int u32;
typedef unsigned short u16;
typedef __attribute__((ext_vector_type(8))) short bf16x8;   // 8 bf16 = 4 VGPRs
typedef __attribute__((ext_vector_type(4))) float f32x4;

__device__ __forceinline__ float bflo(u32 u) {
    union { u32 i; float f; } c; c.i = u << 16; return c.f;
}
__device__ __forceinline__ float bfhi(u32 u) {
    union { u32 i; float f; } c; c.i = u & 0xffff0000u; return c.f;
}
__device__ __forceinline__ u32 pack_bf2(float a, float b) {
    union { float f; u32 i; } ca, cb; ca.f = a; cb.f = b;
    u32 ra = (ca.i + 0x7fffu + ((ca.i >> 16) & 1u)) >> 16;
    u32 rb = (cb.i + 0x7fffu + ((cb.i >> 16) & 1u)) & 0xffff0000u;
    return ra | rb;
}

__device__ __forceinline__ int edge_at(const void* ei, int is64, int which, int i) {
    if (is64) return (int)((const long long*)ei)[(size_t)which * N_EDGES + i];
    return ((const int*)ei)[which * N_EDGES + i];
}

// per-block edge dtype detection: odd 32-bit words of the first 256 entries are
// all zero iff layout is int64 (values < 2^31).
__device__ __forceinline__ int detect_is64(const void* ei, int t, int* s_is32) {
    if (t == 0) *s_is32 = 0;
    __syncthreads();
    if (t < 256) {
        int vv = ((const int*)ei)[2 * t + 1];
        if (vv != 0) atomicOr(s_is32, 1);
    }
    __syncthreads();
    return (*s_is32 == 0);
}

// ---------------- bucketed CSR build (2 passes, slab-allocated) ----------------

// partition edges into per-bucket slabs of ebuf as packed (dst<<16)|src.
// bcur pre-initialized to slab bases (b*SLAB) by k_wsplit -> no histogram pass.
__global__ __launch_bounds__(256) void k_scatter1(const void* __restrict__ ei,
                                                  int* __restrict__ bcur,
                                                  u32* __restrict__ ebuf) {
    __shared__ int h[NB], gbase[NB], lc[NB];
    __shared__ int s_is32;
    int t = threadIdx.x;
    int is64 = detect_is64(ei, t, &s_is32);
    for (int i = t; i < NB; i += 256) { h[i] = 0; lc[i] = 0; }
    __syncthreads();
    int base = blockIdx.x * CH;

    u32 p[CH / 256];
    #pragma unroll
    for (int j = 0; j < CH / 256; ++j) {
        int i = base + j * 256 + t;
        if (i < N_EDGES) {
            int s = edge_at(ei, is64, 0, i);
            int d = edge_at(ei, is64, 1, i);
            p[j] = (u32)s | ((u32)d << 16);
            atomicAdd(&h[d >> 8], 1);
        }
    }
    __syncthreads();
    for (int i = t; i < NB; i += 256) if (h[i]) gbase[i] = atomicAdd(&bcur[i], h[i]);
    __syncthreads();
    #pragma unroll
    for (int j = 0; j < CH / 256; ++j) {
        int i = base + j * 256 + t;
        if (i < N_EDGES) {
            int b = (int)(p[j] >> 24);               // dst >> 8
            int lp = atomicAdd(&lc[b], 1);
            ebuf[gbase[b] + lp] = p[j];              // block-private contiguous run: L2-local
        }
    }
}

// per-bucket: LDS per-node counts/cursors; emit cnt, rowstart, dinv, colidx.
// colidx shares the slab geometry (gaps between buckets are fine: aggs use
// rowstart+cnt only).
__global__ __launch_bounds__(256) void k_scatter2(const u32* __restrict__ ebuf,
                                                  const int* __restrict__ bcur,
                                                  int* __restrict__ rowstart,
                                                  int* __restrict__ cnt,
                                                  float* __restrict__ dinv,
                                                  int* __restrict__ colidx) {
    __shared__ int h2[256], lofs[256], cur[256], sm[256];
    int b = blockIdx.x, t = threadIdx.x;
    int e0 = b * SLAB, ne = bcur[b] - e0;
    h2[t] = 0; cur[t] = 0;
    __syncthreads();
    for (int i = t; i < ne; i += 256) {
        u32 p = ebuf[e0 + i];
        atomicAdd(&h2[(p >> 16) & 255], 1);
    }
    __syncthreads();
    int v = h2[t]; sm[t] = v; __syncthreads();
    for (int off = 1; off < 256; off <<= 1) {
        int a = (t >= off) ? sm[t - off] : 0;
        __syncthreads();
        sm[t] += a;
        __syncthreads();
    }
    lofs[t] = sm[t] - v;
    __syncthreads();
    int node = (b << 8) + t;
    if (node < N_NODES) {
        rowstart[node] = e0 + lofs[t];
        cnt[node] = v;
        dinv[node] = rsqrtf(1.0f + (float)v);
    }
    for (int i = t; i < ne; i += 256) {
        u32 p = ebuf[e0 + i];
        int dl = (p >> 16) & 255;
        int lp = atomicAdd(&cur[dl], 1);
        colidx[e0 + lofs[dl] + lp] = (int)(p & 0xffffu);
    }
}

// ------ W pre-split (both layers, truncation split: hi+lo == w exactly in f32) ------
// also initializes bcur to slab bases (replaces histogram + memset dispatches).
__global__ void k_wsplit(const float* __restrict__ W1, u16* __restrict__ t1h,
                         u16* __restrict__ t1l, const float* __restrict__ W2,
                         u16* __restrict__ t2h, u16* __restrict__ t2l,
                         int* __restrict__ bcur) {
    int i = blockIdx.x * 256 + threadIdx.x;
    if (i < NB) bcur[i] = i * SLAB;
    if (i < D_IN * D_HID) {
        int k = i / D_HID, c = i - k * D_HID;
        u32 bits = __float_as_uint(W1[i]);
        u32 hb = bits & 0xffff0000u;
        float lo = __uint_as_float(bits) - __uint_as_float(hb);
        t1h[(size_t)c * D_IN + k] = (u16)(hb >> 16);
        t1l[(size_t)c * D_IN + k] = (u16)(__float_as_uint(lo) >> 16);
    }
    int j = i - D_IN * D_HID;
    if (j >= 0 && j < D_HID * D_OUT) {
        int k = j / D_OUT, c = j - k * D_OUT;
        u32 bits = __float_as_uint(W2[j]);
        u32 hb = bits & 0xffff0000u;
        float lo = __uint_as_float(bits) - __uint_as_float(hb);
        t2h[(size_t)c * D_HID + k] = (u16)(hb >> 16);
        t2l[(size_t)c * D_HID + k] = (u16)(__float_as_uint(lo) >> 16);
    }
}

// ---- MFMA GEMM (A = f32): Cp[r,:] = pack_bf16( (A[r,:]@W) * dinv[r] ) ----
// BM=128, 4 waves x (2x16 rows, NF cols). K-step 32. Trunc hi/lo split, 3-term MFMA.
template <int K, int NF>
__global__ __launch_bounds__(256) void k_gemm_mfma(
    const float* __restrict__ A, const u16* __restrict__ tHi,
    const u16* __restrict__ tLo, const float* __restrict__ dinv,
    u32* __restrict__ Cp, int M) {
    constexpr int NT = NF / 16;
    constexpr int LDK = 40;
    __shared__ u16 aH[128][LDK], aL[128][LDK];
    __shared__ u16 wH[NF][LDK], wL[NF][LDK];

    const int t = threadIdx.x;
    const int lane = t & 63, wv = t >> 6;
    const int m0 = blockIdx.x * 128;
    const int lr = lane & 15, lk = (lane >> 4) * 8;

    f32x4 acc[2][NT] = {};

    const int arow = t >> 1;
    const int akq = (t & 1) * 16;
    const bool aok = (m0 + arow) < M;
    const float* asrc = A + (size_t)(m0 + arow) * K + akq;

    for (int ks = 0; ks < K; ks += 32) {
        {
            float f[16];
            #pragma unroll
            for (int j = 0; j < 16; ++j) f[j] = 0.0f;
            if (aok) {
                const float4* p = (const float4*)(asrc + ks);
                float4 v0 = p[0], v1 = p[1], v2 = p[2], v3 = p[3];
                f[0] = v0.x; f[1] = v0.y; f[2]  = v0.z; f[3]  = v0.w;
                f[4] = v1.x; f[5] = v1.y; f[6]  = v1.z; f[7]  = v1.w;
                f[8] = v2.x; f[9] = v2.y; f[10] = v2.z; f[11] = v2.w;
                f[12] = v3.x; f[13] = v3.y; f[14] = v3.z; f[15] = v3.w;
            }
            u32 hp[8], lp[8];
            #pragma unroll
            for (int q = 0; q < 8; ++q) {
                u32 b0 = __float_as_uint(f[2 * q]);
                u32 b1 = __float_as_uint(f[2 * q + 1]);
                u32 h0 = b0 & 0xffff0000u, h1 = b1 & 0xffff0000u;
                float l0 = f[2 * q] - __uint_as_float(h0);
                float l1 = f[2 * q + 1] - __uint_as_float(h1);
                hp[q] = (h0 >> 16) | h1;
                lp[q] = (__float_as_uint(l0) >> 16) | (__float_as_uint(l1) & 0xffff0000u);
            }
            *(uint4*)&aH[arow][akq + 0] = make_uint4(hp[0], hp[1], hp[2], hp[3]);
            *(uint4*)&aH[arow][akq + 8] = make_uint4(hp[4], hp[5], hp[6], hp[7]);
            *(uint4*)&aL[arow][akq + 0] = make_uint4(lp[0], lp[1], lp[2], lp[3]);
            *(uint4*)&aL[arow][akq + 8] = make_uint4(lp[4], lp[5], lp[6], lp[7]);
        }
        #pragma unroll
        for (int idx = t; idx < NF * 4; idx += 256) {
            int col = idx >> 2;
            int k8 = (idx & 3) * 8;
            *(uint4*)&wH[col][k8] = *(const uint4*)&tHi[(size_t)col * K + ks + k8];
            *(uint4*)&wL[col][k8] = *(const uint4*)&tLo[(size_t)col * K + ks + k8];
        }
        __syncthreads();

        bf16x8 afH[2], afL[2];
        #pragma unroll
        for (int mt = 0; mt < 2; ++mt) {
            int r = wv * 32 + mt * 16 + lr;
            afH[mt] = *(const bf16x8*)&aH[r][lk];
            afL[mt] = *(const bf16x8*)&aL[r][lk];
        }
        #pragma unroll
        for (int nt = 0; nt < NT; ++nt) {
            bf16x8 bh = *(const bf16x8*)&wH[nt * 16 + lr][lk];
            bf16x8 bl = *(const bf16x8*)&wL[nt * 16 + lr][lk];
            #pragma unroll
            for (int mt = 0; mt < 2; ++mt) {
                acc[mt][nt] = __builtin_amdgcn_mfma_f32_16x16x32_bf16(afH[mt], bh, acc[mt][nt], 0, 0, 0);
                acc[mt][nt] = __builtin_amdgcn_mfma_f32_16x16x32_bf16(afL[mt], bh, acc[mt][nt], 0, 0, 0);
                acc[mt][nt] = __builtin_amdgcn_mfma_f32_16x16x32_bf16(afH[mt], bl, acc[mt][nt], 0, 0, 0);
            }
        }
        __syncthreads();
    }

    #pragma unroll
    for (int mt = 0; mt < 2; ++mt) {
        #pragma unroll
        for (int r = 0; r < 4; ++r) {
            int row = m0 + wv * 32 + mt * 16 + (lane >> 4) * 4 + r;
            float dv = (row < M) ? dinv[row] : 0.0f;
            #pragma unroll
            for (int nt = 0; nt < NT; ++nt) {
                float v = acc[mt][nt][r] * dv;
                float vn = __shfl_xor(v, 1);
                if (!(lane & 1) && row < M) {
                    Cp[(size_t)row * (NF / 2) + nt * 8 + (lr >> 1)] = pack_bf2(v, vn);
                }
            }
        }
    }
}

// ---------------- fused aggregate + bias (+relu) + sigmoid gate ----------------
// 256-thread blocks, 4 nodes/block (one per wave); 8 neighbor rows in flight.
// (round-3 structure: the best-measured aggregation form)

__global__ __launch_bounds__(256) void k_agg1(
        const u32* __restrict__ hs, const int* __restrict__ rowstart,
        const int* __restrict__ cnt, const int* __restrict__ colidx,
        const float* __restrict__ dinv,
        const float* __restrict__ b, const float* __restrict__ aw,
        const float* __restrict__ ab, float* __restrict__ out) {
    int v = blockIdx.x * 4 + (threadIdx.x >> 6);
    int l = threadIdx.x & 63;
    if (v >= N_NODES) return;
    float dv = dinv[v];
    u32 su = hs[(size_t)v * 64 + l];
    float ax = bflo(su), ay = bfhi(su);
    int start = rowstart[v], len = cnt[v];
    const int* cx = colidx + start;
    int j = 0;
    for (; j + 8 <= len; j += 8) {
        int s0 = cx[j], s1 = cx[j + 1], s2 = cx[j + 2], s3 = cx[j + 3];
        int s4 = cx[j + 4], s5 = cx[j + 5], s6 = cx[j + 6], s7 = cx[j + 7];
        u32 u0 = hs[(size_t)s0 * 64 + l];
        u32 u1 = hs[(size_t)s1 * 64 + l];
        u32 u2 = hs[(size_t)s2 * 64 + l];
        u32 u3 = hs[(size_t)s3 * 64 + l];
        u32 u4 = hs[(size_t)s4 * 64 + l];
        u32 u5 = hs[(size_t)s5 * 64 + l];
        u32 u6 = hs[(size_t)s6 * 64 + l];
        u32 u7 = hs[(size_t)s7 * 64 + l];
        ax += bflo(u0) + bflo(u1) + bflo(u2) + bflo(u3)
            + bflo(u4) + bflo(u5) + bflo(u6) + bflo(u7);
        ay += bfhi(u0) + bfhi(u1) + bfhi(u2) + bfhi(u3)
            + bfhi(u4) + bfhi(u5) + bfhi(u6) + bfhi(u7);
    }
    for (; j + 4 <= len; j += 4) {
        int s0 = cx[j], s1 = cx[j + 1], s2 = cx[j + 2], s3 = cx[j + 3];
        u32 u0 = hs[(size_t)s0 * 64 + l];
        u32 u1 = hs[(size_t)s1 * 64 + l];
        u32 u2 = hs[(size_t)s2 * 64 + l];
        u32 u3 = hs[(size_t)s3 * 64 + l];
        ax += bflo(u0) + bflo(u1) + bflo(u2) + bflo(u3);
        ay += bfhi(u0) + bfhi(u1) + bfhi(u2) + bfhi(u3);
    }
    for (; j < len; ++j) {
        u32 u = hs[(size_t)cx[j] * 64 + l];
        ax += bflo(u); ay += bfhi(u);
    }
    float2 bp = ((const float2*)b)[l];
    ax = fmaxf(ax * dv + bp.x, 0.0f);
    ay = fmaxf(ay * dv + bp.y, 0.0f);
    float2 ap = ((const float2*)aw)[l];
    float p = ax * ap.x + ay * ap.y;
    for (int off = 32; off; off >>= 1) p += __shfl_xor(p, off);
    float g = 1.0f / (1.0f + expf(-(p + ab[0])));
    ((float2*)out)[(size_t)v * 64 + l] = make_float2(ax * g, ay * g);
}

__global__ __launch_bounds__(256) void k_agg2(
        const u32* __restrict__ hs, const int* __restrict__ rowstart,
        const int* __restrict__ cnt, const int* __restrict__ colidx,
        const float* __restrict__ dinv,
        const float* __restrict__ b, const float* __restrict__ aw,
        const float* __restrict__ ab, float* __restrict__ out) {
    int v = blockIdx.x * 4 + (threadIdx.x >> 6);
    int l = threadIdx.x & 63;
    if (v >= N_NODES) return;
    int c = l & 31, half = l >> 5;
    float dv = dinv[v];
    float ax = 0.0f, ay = 0.0f;
    if (half == 0) {
        u32 su = hs[(size_t)v * 32 + c];
        ax = bflo(su); ay = bfhi(su);
    }
    int start = rowstart[v], len = cnt[v];
    const int* cx = colidx + start;
    int j = half;
    for (; j + 6 < len; j += 8) {
        int s0 = cx[j], s1 = cx[j + 2], s2 = cx[j + 4], s3 = cx[j + 6];
        u32 u0 = hs[(size_t)s0 * 32 + c];
        u32 u1 = hs[(size_t)s1 * 32 + c];
        u32 u2 = hs[(size_t)s2 * 32 + c];
        u32 u3 = hs[(size_t)s3 * 32 + c];
        ax += bflo(u0) + bflo(u1) + bflo(u2) + bflo(u3);
        ay += bfhi(u0) + bfhi(u1) + bfhi(u2) + bfhi(u3);
    }
    for (; j + 2 < len; j += 4) {
        int s0 = cx[j], s1 = cx[j + 2];
        u32 u0 = hs[(size_t)s0 * 32 + c];
        u32 u1 = hs[(size_t)s1 * 32 + c];
        ax += bflo(u0) + bflo(u1);
        ay += bfhi(u0) + bfhi(u1);
    }
    if (j < len) {
        u32 u = hs[(size_t)cx[j] * 32 + c];
        ax += bflo(u); ay += bfhi(u);
    }
    ax += __shfl_xor(ax, 32);
    ay += __shfl_xor(ay, 32);
    float2 bp = ((const float2*)b)[c];
    ax = ax * dv + bp.x;
    ay = ay * dv + bp.y;
    float2 ap = ((const float2*)aw)[c];
    float p = ax * ap.x + ay * ap.y;
    for (int off = 16; off; off >>= 1) p += __shfl_xor(p, off);
    float g = 1.0f / (1.0f + expf(-(p + ab[0])));
    if (half == 0) ((float2*)out)[(size_t)v * 32 + c] = make_float2(ax * g, ay * g);
}

// ---------------- launch ----------------

static inline size_t align_up(size_t x, size_t a) { return (x + a - 1) & ~(a - 1); }

extern "C" void kernel_launch(void* const* d_in, const int* in_sizes, int n_in,
                              void* d_out, int out_size, void* d_ws, size_t ws_size,
                              hipStream_t stream) {
    const float* x   = (const float*)d_in[0];
    const void*  ei  = d_in[1];
    const float* W1  = (const float*)d_in[2];
    const float* b1  = (const float*)d_in[3];
    const float* W2  = (const float*)d_in[4];
    const float* b2  = (const float*)d_in[5];
    const float* aw1 = (const float*)d_in[6];
    const float* ab1 = (const float*)d_in[7];
    const float* aw2 = (const float*)d_in[8];
    const float* ab2 = (const float*)d_in[9];
    float* out = (float*)d_out;

    char* w = (char*)d_ws;
    size_t off = 0;
    int*   bcur     = (int*)(w + off); off = align_up(off + NB * 4, 256);
    int*   cnt      = (int*)(w + off); off = align_up(off + N_NODES * 4, 256);
    int*   rowstart = (int*)(w + off); off = align_up(off + N_NODES * 4, 256);
    float* dinv     = (float*)(w + off); off = align_up(off + N_NODES * 4, 256);
    u32*   ebuf     = (u32*)(w + off); off = align_up(off + (size_t)NB * SLAB * 4, 256);
    int*   colidx   = (int*)(w + off); off = align_up(off + (size_t)NB * SLAB * 4, 256);
    u32*   h1s      = (u32*)(w + off); off = align_up(off + (size_t)N_NODES * 64 * 4, 256);
    float* h1g      = (float*)(w + off); off = align_up(off + (size_t)N_NODES * D_HID * 4, 256);
    u32*   h2s      = (u32*)(w + off); off = align_up(off + (size_t)N_NODES * 32 * 4, 256);
    u16*   wt1h     = (u16*)(w + off); off = align_up(off + (size_t)D_IN * D_HID * 2, 256);
    u16*   wt1l     = (u16*)(w + off); off = align_up(off + (size_t)D_IN * D_HID * 2, 256);
    u16*   wt2h     = (u16*)(w + off); off = align_up(off + (size_t)D_HID * D_OUT * 2, 256);
    u16*   wt2l     = (u16*)(w + off); off = align_up(off + (size_t)D_HID * D_OUT * 2, 256);
    (void)ws_size; (void)out_size; (void)n_in; (void)in_sizes;

    // wsplit also initializes bcur to slab bases (no memset / histogram dispatch)
    k_wsplit<<<(D_IN * D_HID + D_HID * D_OUT + 255) / 256, 256, 0, stream>>>(
        W1, wt1h, wt1l, W2, wt2h, wt2l, bcur);

    k_scatter1<<<(N_EDGES + CH - 1) / CH, 256, 0, stream>>>(ei, bcur, ebuf);
    k_scatter2<<<NB, 256, 0, stream>>>(ebuf, bcur, rowstart, cnt, dinv, colidx);

    // layer 1: h1s = pack_bf16((x @ W1) * dinv), split-bf16 MFMA
    k_gemm_mfma<D_IN, D_HID><<<(N_NODES + 127) / 128, 256, 0, stream>>>(
        x, wt1h, wt1l, dinv, h1s, N_NODES);
    k_agg1<<<(N_NODES + 3) / 4, 256, 0, stream>>>(
        h1s, rowstart, cnt, colidx, dinv, b1, aw1, ab1, h1g);

    // layer 2: h2s = pack_bf16((h1g @ W2) * dinv), split-bf16 MFMA
    k_gemm_mfma<D_HID, D_OUT><<<(N_NODES + 127) / 128, 256, 0, stream>>>(
        h1g, wt2h, wt2l, dinv, h2s, N_NODES);
    k_agg2<<<(N_NODES + 3) / 4, 256, 0, stream>>>(
        h2s, rowstart, cnt, colidx, dinv, b2, aw2, ab2, out);
}